// Round 10
// baseline (6636.993 us; speedup 1.0000x reference)
//
#include <hip/hip_runtime.h>
#include <hip/hip_fp16.h>

typedef _Float16 f16;
typedef _Float16 f16x2 __attribute__((ext_vector_type(2)));
typedef _Float16 f16x8 __attribute__((ext_vector_type(8)));
typedef float f32x4 __attribute__((ext_vector_type(4)));
typedef unsigned int u32;

#define BATCH 32
#define SEQT  2048
#define DIN   256
#define HU    256
#define G4    1024          // 4*H
#define MROWS (BATCH*SEQT)  // 65536

// ---- workspace layout (bytes) ----
// xw   f16 [65536][1024] @ 0            134217728
// xh   f16 [65536][256]  @ 134217728     33554432
// wt   f16 [1024][256]   @ 167772160       524288
// upk4 u32 [32][1024][4] @ 168296448       524288   (chunk-major U)
// hx   u32 [2][32][4][32]@ 168820736        32768   (h exchange, PARITY dbuf)
// flg  int [32][4][8]    @ 168853504         4096   (flags, 32B stride)
#define WS_XW 0
#define WS_XH 134217728UL
#define WS_WT 167772160UL
#define WS_UP 168296448UL
#define WS_HX 168820736UL
#define WS_FLG 168853504UL
#define WS_NEED 168857600UL

// ---------------- prep kernels ----------------
// upk4 chunk-major: chunk c (= h-pairs 4c..4c+3 = k 8c..8c+7), col j:
// dword (c*1024 + j)*4 + (p&3). One uint4 = one chunk of one column.
__global__ void pack_u(const float* __restrict__ U, u32* __restrict__ upk4) {
    int idx = blockIdx.x * 256 + threadIdx.x;      // 128*1024
    int p = idx >> 10, j = idx & 1023;
    f16x2 h;
    h.x = (f16)U[(2 * p) * G4 + j];
    h.y = (f16)U[(2 * p + 1) * G4 + j];
    upk4[(((p >> 2) * 1024 + j) << 2) + (p & 3)] = __builtin_bit_cast(u32, h);
}

__global__ void conv_x(const float* __restrict__ x, f16* __restrict__ xh) {
    int idx = blockIdx.x * 256 + threadIdx.x;      // 65536*32
    int row = idx >> 5, c = idx & 31;
    const float4* src = (const float4*)(x + row * 256 + c * 8);
    float4 v0 = src[0], v1 = src[1];
    f16x8 o;
    o[0] = (f16)v0.x; o[1] = (f16)v0.y; o[2] = (f16)v0.z; o[3] = (f16)v0.w;
    o[4] = (f16)v1.x; o[5] = (f16)v1.y; o[6] = (f16)v1.z; o[7] = (f16)v1.w;
    *(f16x8*)(xh + row * 256 + c * 8) = o;
}

__global__ void conv_w(const float* __restrict__ W, f16* __restrict__ wt) {
    int idx = blockIdx.x * 256 + threadIdx.x;      // 1024*32
    int j = idx >> 5, c = idx & 31;
    f16x8 o;
#pragma unroll
    for (int i = 0; i < 8; ++i) o[i] = (f16)W[(c * 8 + i) * G4 + j];
    *(f16x8*)(wt + j * 256 + c * 8) = o;
}

// ---------------- xW GEMM: [65536,256]x[256,1024] fp16 MFMA ----------------
__launch_bounds__(256)
__global__ void gemm_xw(const f16* __restrict__ xh, const f16* __restrict__ wt,
                        const float* __restrict__ bias, f16* __restrict__ xw) {
    __shared__ __align__(16) f16 As[128 * 256];   // 64 KB, swizzled chunks
    __shared__ __align__(16) f16 Bs[128 * 256];   // 64 KB
    int mt = blockIdx.x, nt = blockIdx.y;
    int t = threadIdx.x, lane = t & 63, w = t >> 6;

    const uint4* Ag = (const uint4*)(xh + (size_t)mt * 128 * 256);
    const uint4* Bg = (const uint4*)(wt + (size_t)nt * 128 * 256);
#pragma unroll
    for (int i = 0; i < 16; ++i) {
        int o16 = t + i * 256;            // 16B chunk id 0..4095
        int row = o16 >> 5, c = o16 & 31;
        uint4 va = Ag[o16];
        uint4 vb = Bg[o16];
        int sw = c ^ (row & 7);
        *(uint4*)((char*)As + row * 512 + sw * 16) = va;
        *(uint4*)((char*)Bs + row * 512 + sw * 16) = vb;
    }
    __syncthreads();

    int wr = w >> 1, wc = w & 1;
    f32x4 acc[4][4];
#pragma unroll
    for (int mi = 0; mi < 4; ++mi)
#pragma unroll
        for (int ni = 0; ni < 4; ++ni) acc[mi][ni] = (f32x4){0.f, 0.f, 0.f, 0.f};

    int rA = lane & 15;
    int kg = lane >> 4;    // 0..3 -> k-offset group of 8
#pragma unroll
    for (int ks = 0; ks < 8; ++ks) {
        f16x8 af[4], bf[4];
#pragma unroll
        for (int mi = 0; mi < 4; ++mi) {
            int row = wr * 64 + mi * 16 + rA;
            int c = ks * 4 + kg;
            af[mi] = *(const f16x8*)((const char*)As + row * 512 + ((c ^ (row & 7)) * 16));
        }
#pragma unroll
        for (int ni = 0; ni < 4; ++ni) {
            int row = wc * 64 + ni * 16 + rA;
            int c = ks * 4 + kg;
            bf[ni] = *(const f16x8*)((const char*)Bs + row * 512 + ((c ^ (row & 7)) * 16));
        }
#pragma unroll
        for (int mi = 0; mi < 4; ++mi)
#pragma unroll
            for (int ni = 0; ni < 4; ++ni)
                acc[mi][ni] = __builtin_amdgcn_mfma_f32_16x16x32_f16(af[mi], bf[ni], acc[mi][ni], 0, 0, 0);
    }

    // epilogue: C/D layout col=lane&15, row=(lane>>4)*4+q
    int r4 = (lane >> 4) * 4, cc = lane & 15;
    float bv[4];
#pragma unroll
    for (int ni = 0; ni < 4; ++ni) bv[ni] = bias[nt * 128 + wc * 64 + ni * 16 + cc];
#pragma unroll
    for (int mi = 0; mi < 4; ++mi)
#pragma unroll
        for (int ni = 0; ni < 4; ++ni)
#pragma unroll
            for (int q = 0; q < 4; ++q) {
                int grow = mt * 128 + wr * 64 + mi * 16 + r4 + q;
                int gcol = nt * 128 + wc * 64 + ni * 16 + cc;
                xw[(size_t)grow * 1024 + gcol] = (f16)(acc[mi][ni][q] + bv[ni]);
            }
}

// ---------------- recurrence ----------------
__device__ __forceinline__ float fdot2u(u32 u, u32 h, float acc) {
    return __builtin_amdgcn_fdot2(__builtin_bit_cast(f16x2, u),
                                  __builtin_bit_cast(f16x2, h), acc, false);
}
__device__ __forceinline__ float sigm(float x) {
    return 1.0f / (1.0f + __expf(-x));
}
__device__ __forceinline__ float tanh_f(float x) {
    x = fminf(fmaxf(x, -15.0f), 15.0f);
    float e = __expf(2.0f * x);
    return (e - 1.0f) / (e + 1.0f);
}

// ---- R10 = R9 (U fully in LDS, 4 WGs/batch) + PARITY-dbuf h exchange ----
// R9 failed correctness: single-buffer hx has a step-skew race (a partner
// can overwrite h(st-1) with h(st), or read while we overwrite, since
// flag>=st only proves step st-1 finished). Fix: publish h(st) to
// hx[st&1]; read h(st-1) from hx[(st-1)&1]. Overwriting parity slot with
// h(st) requires partners' flags>=st => they finished step st-1 => they
// already consumed h(st-2), the value destroyed. No extra sync; flags
// monotone; buffers zeroed per launch (h(-1)=0 read from parity 1).
//
// Design rationale (R1-R8): backend remats loop-invariant U from global
// every step (~377 KB/step/CU was the R6 step time). Here the U slice
// (256 cols x 512 B = 128 KB) lives entirely in LDS: zero steady-state
// U traffic on any global path. WG q owns units q*64..q*64+63 (col =
// g*64+ul locally), updates its own c/h; only h halves cross WGs.

__launch_bounds__(256)
__global__ void lstm_rec(const uint4* __restrict__ upk4, const f16* __restrict__ xw,
                         float* __restrict__ out, u32* hx, int* flg) {
    __shared__ __align__(16) u32 ulds[256 * 128];  // 128 KB: col-local*128 + swz(chunk)*4
    __shared__ __align__(16) u32 hpair[128];       // full h as 128 f16-pair dwords
    __shared__ __align__(16) float gbuf[256];      // activated gates (g*64+ul)

    int wg = blockIdx.x, b = wg >> 2, q = wg & 3;
    int t = threadIdx.x;
    int g = t >> 6, ul = t & 63;                   // gate, local unit
    int gcol = g * 256 + q * 64 + ul;              // global gate-column

    // stage this WG's U slice: 32 chunks per column, swizzled
    for (int c = 0; c < 32; ++c) {
        uint4 v = upk4[c * 1024 + gcol];
        *(uint4*)&ulds[t * 128 + ((c ^ (t & 7)) << 2)] = v;
    }
    if (t < 128) hpair[t] = 0u;

    u32* hx_b  = hx + b * 128;                     // + parity*4096
    int* flg_b = flg + b * 32;                     // 4 flags, 8-dword stride

    float c_state = 0.0f;
    const f16* xp = xw + (size_t)b * SEQT * G4;
    float* op = out + (size_t)b * SEQT * HU + q * 64;
    f16 xa = xp[gcol];
    __syncthreads();

    for (int st = 0; st < SEQT; ++st) {
        // read parity: h(st-1) lives in hx[(st-1)&1]; write parity: st&1
        u32* hx_rd = hx_b + (((st + 1) & 1) << 12);
        u32* hx_wr = hx_b + ((st & 1) << 12);

        float a0 = (float)xa, a1 = 0.f, a2 = 0.f, a3 = 0.f;
        if (st < SEQT - 1) xa = xp[G4 + gcol];
        xp += G4;

        // ---- own-k MAC: chunks 8q..8q+7 (h half is WG-local) ----
#pragma unroll
        for (int i = 0; i < 8; ++i) {
            int c = q * 8 + i;
            uint4 hv = *(const uint4*)&hpair[c << 2];
            uint4 u4 = *(const uint4*)&ulds[t * 128 + ((c ^ (t & 7)) << 2)];
            a0 = fdot2u(u4.x, hv.x, a0);
            a1 = fdot2u(u4.y, hv.y, a1);
            a2 = fdot2u(u4.z, hv.z, a2);
            a3 = fdot2u(u4.w, hv.w, a3);
        }

        // ---- wait for partners' h(st-1): flag >= st ----
        if (t < 3) {
            int p = t + (t >= q);
            int spins = 0;
            while (__hip_atomic_load(&flg_b[p * 8], __ATOMIC_ACQUIRE,
                                     __HIP_MEMORY_SCOPE_AGENT) < st &&
                   spins < (1 << 22)) {
                __builtin_amdgcn_s_sleep(1);
                ++spins;
            }
        }
        __syncthreads();
        if (t < 96) {
            int p = t >> 5, d = t & 31;
            int pidx = p + (p >= q);
            hpair[pidx * 32 + d] =
                __hip_atomic_load(&hx_rd[pidx * 32 + d], __ATOMIC_RELAXED,
                                  __HIP_MEMORY_SCOPE_AGENT);
        }
        __syncthreads();

        // ---- partner-k MACs: the other 24 chunks ----
#pragma unroll
        for (int j = 0; j < 4; ++j) {
            if (j == q) continue;                  // wave-uniform skip
#pragma unroll
            for (int i = 0; i < 8; ++i) {
                int c = j * 8 + i;
                uint4 hv = *(const uint4*)&hpair[c << 2];
                uint4 u4 = *(const uint4*)&ulds[t * 128 + ((c ^ (t & 7)) << 2)];
                a0 = fdot2u(u4.x, hv.x, a0);
                a1 = fdot2u(u4.y, hv.y, a1);
                a2 = fdot2u(u4.z, hv.z, a2);
                a3 = fdot2u(u4.w, hv.w, a3);
            }
        }
        float a = (a0 + a1) + (a2 + a3);

        // gate = g (wave-uniform): 0=i 1=f 2=g(tanh) 3=o
        float act = (g == 2) ? tanh_f(a) : sigm(a);
        gbuf[t] = act;
        __syncthreads();

        // ---- c/h update for own 64 units ----
        if (t < 64) {
            float gi = gbuf[t];
            float gf = gbuf[64 + t];
            float gg = gbuf[128 + t];
            float go = gbuf[192 + t];
            c_state = gf * c_state + gi * gg;
            float h = go * tanh_f(c_state);
            op[t] = h;
            ((f16*)hpair)[q * 64 + t] = (f16)h;
        }
        op += HU;
        __syncthreads();

        // ---- publish own h half (parity st&1) + flag ----
        if (t < 32)
            __hip_atomic_store(&hx_wr[q * 32 + t], hpair[q * 32 + t],
                               __ATOMIC_RELAXED, __HIP_MEMORY_SCOPE_AGENT);
        __syncthreads();
        if (t == 0)
            __hip_atomic_store(&flg_b[q * 8], st + 1, __ATOMIC_RELEASE,
                               __HIP_MEMORY_SCOPE_AGENT);
    }
}

extern "C" void kernel_launch(void* const* d_in, const int* in_sizes, int n_in,
                              void* d_out, int out_size, void* d_ws, size_t ws_size,
                              hipStream_t stream) {
    const float* x    = (const float*)d_in[0];
    const float* W    = (const float*)d_in[1];
    const float* U    = (const float*)d_in[2];
    const float* bias = (const float*)d_in[3];
    float* out = (float*)d_out;

    if (ws_size < WS_NEED) return;  // fail loudly rather than corrupt
    char* ws = (char*)d_ws;
    f16* xw    = (f16*)(ws + WS_XW);
    f16* xh    = (f16*)(ws + WS_XH);
    f16* wt    = (f16*)(ws + WS_WT);
    u32* upk4  = (u32*)(ws + WS_UP);
    u32* hx    = (u32*)(ws + WS_HX);
    int* flg   = (int*)(ws + WS_FLG);

    // zero exchange buffers + flags every call (replay-safe, in-stream)
    hipMemsetAsync(ws + WS_HX, 0, WS_NEED - WS_HX, stream);

    pack_u<<<512, 256, 0, stream>>>(U, upk4);
    conv_x<<<8192, 256, 0, stream>>>(x, xh);
    conv_w<<<128, 256, 0, stream>>>(W, wt);
    gemm_xw<<<dim3(512, 8), 256, 0, stream>>>(xh, wt, bias, xw);
    lstm_rec<<<128, 256, 0, stream>>>((const uint4*)upk4, xw, out, hx, flg);
}

// Round 11
// 6251.019 us; speedup vs baseline: 1.0617x; 1.0617x over previous
//
#include <hip/hip_runtime.h>
#include <hip/hip_fp16.h>

typedef _Float16 f16;
typedef _Float16 f16x2 __attribute__((ext_vector_type(2)));
typedef _Float16 f16x8 __attribute__((ext_vector_type(8)));
typedef float f32x4 __attribute__((ext_vector_type(4)));
typedef unsigned int u32;

#define BATCH 32
#define SEQT  2048
#define DIN   256
#define HU    256
#define G4    1024          // 4*H
#define MROWS (BATCH*SEQT)  // 65536

// ---- workspace layout (bytes) ----
// xw   f16 [65536][1024] @ 0            134217728
// xh   f16 [65536][256]  @ 134217728     33554432
// wt   f16 [1024][256]   @ 167772160       524288
// upk4 u32 [32][1024][4] @ 168296448       524288   (chunk-major U)
// hx   u32 [2][32][4][32]@ 168820736        32768   (h exchange, parity dbuf)
// flg  int [32][4][8]    @ 168853504         4096   (flags, 32B stride)
#define WS_XW 0
#define WS_XH 134217728UL
#define WS_WT 167772160UL
#define WS_UP 168296448UL
#define WS_HX 168820736UL
#define WS_FLG 168853504UL
#define WS_NEED 168857600UL

// ---------------- prep kernels ----------------
__global__ void pack_u(const float* __restrict__ U, u32* __restrict__ upk4) {
    int idx = blockIdx.x * 256 + threadIdx.x;      // 128*1024
    int p = idx >> 10, j = idx & 1023;
    f16x2 h;
    h.x = (f16)U[(2 * p) * G4 + j];
    h.y = (f16)U[(2 * p + 1) * G4 + j];
    upk4[(((p >> 2) * 1024 + j) << 2) + (p & 3)] = __builtin_bit_cast(u32, h);
}

__global__ void conv_x(const float* __restrict__ x, f16* __restrict__ xh) {
    int idx = blockIdx.x * 256 + threadIdx.x;      // 65536*32
    int row = idx >> 5, c = idx & 31;
    const float4* src = (const float4*)(x + row * 256 + c * 8);
    float4 v0 = src[0], v1 = src[1];
    f16x8 o;
    o[0] = (f16)v0.x; o[1] = (f16)v0.y; o[2] = (f16)v0.z; o[3] = (f16)v0.w;
    o[4] = (f16)v1.x; o[5] = (f16)v1.y; o[6] = (f16)v1.z; o[7] = (f16)v1.w;
    *(f16x8*)(xh + row * 256 + c * 8) = o;
}

__global__ void conv_w(const float* __restrict__ W, f16* __restrict__ wt) {
    int idx = blockIdx.x * 256 + threadIdx.x;      // 1024*32
    int j = idx >> 5, c = idx & 31;
    f16x8 o;
#pragma unroll
    for (int i = 0; i < 8; ++i) o[i] = (f16)W[(c * 8 + i) * G4 + j];
    *(f16x8*)(wt + j * 256 + c * 8) = o;
}

// ---------------- xW GEMM: [65536,256]x[256,1024] fp16 MFMA ----------------
__launch_bounds__(256)
__global__ void gemm_xw(const f16* __restrict__ xh, const f16* __restrict__ wt,
                        const float* __restrict__ bias, f16* __restrict__ xw) {
    __shared__ __align__(16) f16 As[128 * 256];   // 64 KB, swizzled chunks
    __shared__ __align__(16) f16 Bs[128 * 256];   // 64 KB
    int mt = blockIdx.x, nt = blockIdx.y;
    int t = threadIdx.x, lane = t & 63, w = t >> 6;

    const uint4* Ag = (const uint4*)(xh + (size_t)mt * 128 * 256);
    const uint4* Bg = (const uint4*)(wt + (size_t)nt * 128 * 256);
#pragma unroll
    for (int i = 0; i < 16; ++i) {
        int o16 = t + i * 256;            // 16B chunk id 0..4095
        int row = o16 >> 5, c = o16 & 31;
        uint4 va = Ag[o16];
        uint4 vb = Bg[o16];
        int sw = c ^ (row & 7);
        *(uint4*)((char*)As + row * 512 + sw * 16) = va;
        *(uint4*)((char*)Bs + row * 512 + sw * 16) = vb;
    }
    __syncthreads();

    int wr = w >> 1, wc = w & 1;
    f32x4 acc[4][4];
#pragma unroll
    for (int mi = 0; mi < 4; ++mi)
#pragma unroll
        for (int ni = 0; ni < 4; ++ni) acc[mi][ni] = (f32x4){0.f, 0.f, 0.f, 0.f};

    int rA = lane & 15;
    int kg = lane >> 4;    // 0..3 -> k-offset group of 8
#pragma unroll
    for (int ks = 0; ks < 8; ++ks) {
        f16x8 af[4], bf[4];
#pragma unroll
        for (int mi = 0; mi < 4; ++mi) {
            int row = wr * 64 + mi * 16 + rA;
            int c = ks * 4 + kg;
            af[mi] = *(const f16x8*)((const char*)As + row * 512 + ((c ^ (row & 7)) * 16));
        }
#pragma unroll
        for (int ni = 0; ni < 4; ++ni) {
            int row = wc * 64 + ni * 16 + rA;
            int c = ks * 4 + kg;
            bf[ni] = *(const f16x8*)((const char*)Bs + row * 512 + ((c ^ (row & 7)) * 16));
        }
#pragma unroll
        for (int mi = 0; mi < 4; ++mi)
#pragma unroll
            for (int ni = 0; ni < 4; ++ni)
                acc[mi][ni] = __builtin_amdgcn_mfma_f32_16x16x32_f16(af[mi], bf[ni], acc[mi][ni], 0, 0, 0);
    }

    // epilogue: C/D layout col=lane&15, row=(lane>>4)*4+q
    int r4 = (lane >> 4) * 4, cc = lane & 15;
    float bv[4];
#pragma unroll
    for (int ni = 0; ni < 4; ++ni) bv[ni] = bias[nt * 128 + wc * 64 + ni * 16 + cc];
#pragma unroll
    for (int mi = 0; mi < 4; ++mi)
#pragma unroll
        for (int ni = 0; ni < 4; ++ni)
#pragma unroll
            for (int q = 0; q < 4; ++q) {
                int grow = mt * 128 + wr * 64 + mi * 16 + r4 + q;
                int gcol = nt * 128 + wc * 64 + ni * 16 + cc;
                xw[(size_t)grow * 1024 + gcol] = (f16)(acc[mi][ni][q] + bv[ni]);
            }
}

// ---------------- recurrence ----------------
__device__ __forceinline__ float fdot2u(u32 u, u32 h, float acc) {
    return __builtin_amdgcn_fdot2(__builtin_bit_cast(f16x2, u),
                                  __builtin_bit_cast(f16x2, h), acc, false);
}
__device__ __forceinline__ float sigm(float x) {
    return 1.0f / (1.0f + __expf(-x));
}
__device__ __forceinline__ float tanh_f(float x) {
    x = fminf(fmaxf(x, -15.0f), 15.0f);
    float e = __expf(2.0f * x);
    return (e - 1.0f) / (e + 1.0f);
}

// ---- R11 = R10 topology with the three measured leaks fixed ----
// R10 (passed, 6.58 ms): SQ_LDS_BANK_CONFLICT=1.34e8 (t*128+xor layout;
// 4 extra cyc per U-read), 256 thr = 1 wave/SIMD (exposed LDS latency),
// cross-XCD exchange. Fixes:
//  1. stride-132 column layout, no xor: bank quad = (col+chunk)&7 — the
//     exact pattern R6 measured at ZERO conflicts.
//  2. 512 threads, 2-way split-k: thread (col, khalf) does 16 chunks;
//     2 waves/SIMD; partials combined via pbuf (+1 barrier).
//  3. XCD co-location: batch's 4 WGs mapped to one XCD assuming
//     xcd = blockIdx%8 round-robin (perf-only assumption).
// Exchange protocol: R10's parity-dbuf + monotone flags, unchanged.

__launch_bounds__(512)
__global__ void lstm_rec(const uint4* __restrict__ upk4, const f16* __restrict__ xw,
                         float* __restrict__ out, u32* hx, int* flg) {
    __shared__ __align__(16) u32 ulds[256 * 132]; // 132 KB; col*132 + chunk*4
    __shared__ __align__(16) u32 hpair[128];      // full h as 128 f16-pair dwords
    __shared__ __align__(16) float pbuf[512];     // split-k partials
    __shared__ __align__(16) float gbuf[256];     // activated gates (g*64+ul)

    int L = blockIdx.x;
    int b = (L & 7) * 4 + (L >> 5);                // batch
    int q = (L >> 3) & 3;                          // quarter
    int t = threadIdx.x;
    int col = t & 255, khalf = t >> 8;             // local gate-col, k-half
    int g = col >> 6, ul = col & 63;
    int gcol = g * 256 + q * 64 + ul;              // global gate-column
    int kh4 = khalf * 4;

    // stage this WG's U slice: 16 chunks per thread
#pragma unroll
    for (int i = 0; i < 16; ++i) {
        int c = khalf * 16 + i;
        *(uint4*)&ulds[col * 132 + (c << 2)] = upk4[c * 1024 + gcol];
    }
    if (t < 128) hpair[t] = 0u;

    u32* hx_b  = hx + b * 128;                     // + parity*4096
    int* flg_b = flg + b * 32;                     // 4 flags, 8-dword stride

    float c_state = 0.0f;
    const f16* xp = xw + (size_t)b * SEQT * G4;
    float* op = out + (size_t)b * SEQT * HU + q * 64;
    f16 xa = (khalf == 0) ? xp[gcol] : (f16)0.0f;
    __syncthreads();

    for (int st = 0; st < SEQT; ++st) {
        u32* hx_rd = hx_b + (((st + 1) & 1) << 12);
        u32* hx_wr = hx_b + ((st & 1) << 12);

        float a0 = (khalf == 0) ? (float)xa : 0.f;
        float a1 = 0.f, a2 = 0.f, a3 = 0.f;
        if (khalf == 0 && st < SEQT - 1) xa = xp[G4 + gcol];
        xp += G4;

        // ---- own-k MAC: 4 chunks (h half is WG-local) ----
#pragma unroll
        for (int i = 0; i < 4; ++i) {
            int c = q * 8 + kh4 + i;
            uint4 hv = *(const uint4*)&hpair[c << 2];
            uint4 u4 = *(const uint4*)&ulds[col * 132 + (c << 2)];
            a0 = fdot2u(u4.x, hv.x, a0);
            a1 = fdot2u(u4.y, hv.y, a1);
            a2 = fdot2u(u4.z, hv.z, a2);
            a3 = fdot2u(u4.w, hv.w, a3);
        }

        // ---- wait for partners' h(st-1): flag >= st ----
        if (t < 3) {
            int p = t + (t >= q);
            int spins = 0;
            while (__hip_atomic_load(&flg_b[p * 8], __ATOMIC_ACQUIRE,
                                     __HIP_MEMORY_SCOPE_AGENT) < st &&
                   spins < (1 << 22)) {
                __builtin_amdgcn_s_sleep(1);
                ++spins;
            }
        }
        __syncthreads();
        if (t < 96) {
            int p = t >> 5, d = t & 31;
            int pidx = p + (p >= q);
            hpair[pidx * 32 + d] =
                __hip_atomic_load(&hx_rd[pidx * 32 + d], __ATOMIC_RELAXED,
                                  __HIP_MEMORY_SCOPE_AGENT);
        }
        __syncthreads();

        // ---- partner-k MACs: 12 chunks ----
#pragma unroll
        for (int j = 0; j < 4; ++j) {
            if (j == q) continue;                  // wave-uniform skip
#pragma unroll
            for (int i = 0; i < 4; ++i) {
                int c = j * 8 + kh4 + i;
                uint4 hv = *(const uint4*)&hpair[c << 2];
                uint4 u4 = *(const uint4*)&ulds[col * 132 + (c << 2)];
                a0 = fdot2u(u4.x, hv.x, a0);
                a1 = fdot2u(u4.y, hv.y, a1);
                a2 = fdot2u(u4.z, hv.z, a2);
                a3 = fdot2u(u4.w, hv.w, a3);
            }
        }
        pbuf[t] = (a0 + a1) + (a2 + a3);
        __syncthreads();

        // ---- combine split-k + activation ----
        if (t < 256) {
            float a = pbuf[t] + pbuf[t + 256];
            float act = ((t >> 6) == 2) ? tanh_f(a) : sigm(a);
            gbuf[t] = act;
        }
        __syncthreads();

        // ---- c/h update for own 64 units ----
        if (t < 64) {
            float gi = gbuf[t];
            float gf = gbuf[64 + t];
            float gg = gbuf[128 + t];
            float go = gbuf[192 + t];
            c_state = gf * c_state + gi * gg;
            float h = go * tanh_f(c_state);
            op[t] = h;
            ((f16*)hpair)[q * 64 + t] = (f16)h;
        }
        op += HU;
        __syncthreads();

        // ---- publish own h half (parity st&1) + flag ----
        if (t < 32)
            __hip_atomic_store(&hx_wr[q * 32 + t], hpair[q * 32 + t],
                               __ATOMIC_RELAXED, __HIP_MEMORY_SCOPE_AGENT);
        __syncthreads();
        if (t == 0)
            __hip_atomic_store(&flg_b[q * 8], st + 1, __ATOMIC_RELEASE,
                               __HIP_MEMORY_SCOPE_AGENT);
    }
}

extern "C" void kernel_launch(void* const* d_in, const int* in_sizes, int n_in,
                              void* d_out, int out_size, void* d_ws, size_t ws_size,
                              hipStream_t stream) {
    const float* x    = (const float*)d_in[0];
    const float* W    = (const float*)d_in[1];
    const float* U    = (const float*)d_in[2];
    const float* bias = (const float*)d_in[3];
    float* out = (float*)d_out;

    if (ws_size < WS_NEED) return;  // fail loudly rather than corrupt
    char* ws = (char*)d_ws;
    f16* xw    = (f16*)(ws + WS_XW);
    f16* xh    = (f16*)(ws + WS_XH);
    f16* wt    = (f16*)(ws + WS_WT);
    u32* upk4  = (u32*)(ws + WS_UP);
    u32* hx    = (u32*)(ws + WS_HX);
    int* flg   = (int*)(ws + WS_FLG);

    // zero exchange buffers + flags every call (replay-safe, in-stream)
    hipMemsetAsync(ws + WS_HX, 0, WS_NEED - WS_HX, stream);

    pack_u<<<512, 256, 0, stream>>>(U, upk4);
    conv_x<<<8192, 256, 0, stream>>>(x, xh);
    conv_w<<<128, 256, 0, stream>>>(W, wt);
    gemm_xw<<<dim3(512, 8), 256, 0, stream>>>(xh, wt, bias, xw);
    lstm_rec<<<128, 512, 0, stream>>>((const uint4*)upk4, xw, out, hx, flg);
}